// Round 1
// baseline (4000.826 us; speedup 1.0000x reference)
//
#include <hip/hip_runtime.h>
#include <math.h>

#define N 16384
#define D 512
#define K 1024
#define NUM_ITERS 10
#define TEMPERATURE 0.1f
#define CONCENTRATION 0.1f
#define EPS 1e-6f

#define TM 32    // points per block in assign
#define TKC 128  // clusters per chunk
#define TD 32    // d-dim per LDS stage

// ---------------- row sum-of-squares (x_sq, c_sq) ----------------
__global__ void rowsq_kernel(const float* __restrict__ x, float* __restrict__ out, int rows) {
    int row = blockIdx.x * 4 + (threadIdx.x >> 6);
    int lane = threadIdx.x & 63;
    if (row >= rows) return;
    const float* r = x + (size_t)row * D;
    float s = 0.f;
    for (int i = lane; i < D; i += 64) { float v = r[i]; s += v * v; }
    for (int off = 32; off > 0; off >>= 1) s += __shfl_down(s, off, 64);
    if (lane == 0) out[row] = s;
}

// ---------------- assign: argmin_k (x_sq - 2*dot + c_sq) ----------------
__global__ __launch_bounds__(256) void assign_kernel(
    const float* __restrict__ feats, const float* __restrict__ cent,
    const float* __restrict__ xsq, const float* __restrict__ csq,
    int* __restrict__ clusters)
{
    __shared__ float Xs[TD][TM + 4];    // [d][p], stride 36 (16B-aligned rows)
    __shared__ float Cs[TD][TKC + 4];   // [d][c], stride 132 (16B-aligned rows)
    __shared__ float Vred[TM][33];
    __shared__ int   Kred[TM][33];

    const int tid = threadIdx.x;
    const int tc = tid & 31;   // cluster group: clusters tc*4 .. tc*4+3 (per chunk)
    const int tp = tid >> 5;   // point group: points tp*4 .. tp*4+3
    const int bp = blockIdx.x * TM;

    float bestv[4]; int bestk[4];
#pragma unroll
    for (int i = 0; i < 4; ++i) { bestv[i] = INFINITY; bestk[i] = 0; }

    for (int kc = 0; kc < K; kc += TKC) {
        float acc[4][4];
#pragma unroll
        for (int i = 0; i < 4; ++i)
#pragma unroll
            for (int j = 0; j < 4; ++j) acc[i][j] = 0.f;

        for (int d0 = 0; d0 < D; d0 += TD) {
            __syncthreads();
            // load Xs: TD*TM = 1024 elems, 4 per thread, coalesced over d
#pragma unroll
            for (int i = 0; i < 4; ++i) {
                int e = i * 256 + tid; int d = e & 31, p = e >> 5;
                Xs[d][p] = feats[(size_t)(bp + p) * D + d0 + d];
            }
            // load Cs: TD*TKC = 4096 elems, 16 per thread
#pragma unroll
            for (int i = 0; i < 16; ++i) {
                int e = i * 256 + tid; int d = e & 31, c = e >> 5;
                Cs[d][c] = cent[(size_t)(kc + c) * D + d0 + d];
            }
            __syncthreads();
#pragma unroll
            for (int d = 0; d < TD; ++d) {
                const float4 xv = *reinterpret_cast<const float4*>(&Xs[d][tp * 4]);
                const float4 cv = *reinterpret_cast<const float4*>(&Cs[d][tc * 4]);
                acc[0][0] += xv.x * cv.x; acc[0][1] += xv.x * cv.y; acc[0][2] += xv.x * cv.z; acc[0][3] += xv.x * cv.w;
                acc[1][0] += xv.y * cv.x; acc[1][1] += xv.y * cv.y; acc[1][2] += xv.y * cv.z; acc[1][3] += xv.y * cv.w;
                acc[2][0] += xv.z * cv.x; acc[2][1] += xv.z * cv.y; acc[2][2] += xv.z * cv.z; acc[2][3] += xv.z * cv.w;
                acc[3][0] += xv.w * cv.x; acc[3][1] += xv.w * cv.y; acc[3][2] += xv.w * cv.z; acc[3][3] += xv.w * cv.w;
            }
        }
        // chunk epilogue: distances + running argmin (k ascending, strict < => first min)
#pragma unroll
        for (int i = 0; i < 4; ++i) {
            int p = tp * 4 + i;
            float xs = xsq[bp + p];
#pragma unroll
            for (int j = 0; j < 4; ++j) {
                int k = kc + tc * 4 + j;
                float dv = xs - 2.0f * acc[i][j] + csq[k];
                if (dv < bestv[i] || (dv == bestv[i] && k < bestk[i])) { bestv[i] = dv; bestk[i] = k; }
            }
        }
    }
    __syncthreads();
#pragma unroll
    for (int i = 0; i < 4; ++i) {
        int p = tp * 4 + i;
        Vred[p][tc] = bestv[i];
        Kred[p][tc] = bestk[i];
    }
    __syncthreads();
    if (tid < TM) {
        float bv = Vred[tid][0]; int bk = Kred[tid][0];
        for (int t = 1; t < 32; ++t) {
            float v = Vred[tid][t]; int k2 = Kred[tid][t];
            if (v < bv || (v == bv && k2 < bk)) { bv = v; bk = k2; }
        }
        clusters[bp + tid] = bk;
    }
}

// ---------------- segment sums (atomic) ----------------
__global__ void accum_kernel(const float* __restrict__ feats, const int* __restrict__ clusters,
                             float* __restrict__ sums, float* __restrict__ counts) {
    int p = blockIdx.x;
    int cl = clusters[p];
    const float* row = feats + (size_t)p * D;
    float* srow = sums + (size_t)cl * D;
    for (int d = threadIdx.x; d < D; d += 256) atomicAdd(&srow[d], row[d]);
    if (threadIdx.x == 0) atomicAdd(&counts[cl], 1.0f);
}

__global__ void update_kernel(float* __restrict__ cent, const float* __restrict__ sums,
                              const float* __restrict__ counts) {
    int idx = blockIdx.x * 256 + threadIdx.x;  // K*D threads
    int k = idx >> 9;  // /D
    float cnt = counts[k];
    if (cnt > 0.f) cent[idx] = sums[idx] / fmaxf(cnt, 1.f);
}

// ---------------- residual^2 segment sum ----------------
__global__ void dist_kernel(const float* __restrict__ feats, const float* __restrict__ cent,
                            const int* __restrict__ clusters, float* __restrict__ dists) {
    int p = blockIdx.x;
    int cl = clusters[p];
    const float* row = feats + (size_t)p * D;
    const float* crow = cent + (size_t)cl * D;
    float* drow = dists + (size_t)cl * D;
    for (int d = threadIdx.x; d < D; d += 256) {
        float r = row[d] - crow[d];
        atomicAdd(&drow[d], r * r);
    }
}

// ---------------- loss ----------------
__global__ void sump_kernel(const float* __restrict__ dists, double* __restrict__ S) {
    int idx = blockIdx.x * 256 + threadIdx.x;
    float v = expf(-(dists[idx] / CONCENTRATION));
    __shared__ float red[4];
    for (int off = 32; off > 0; off >>= 1) v += __shfl_down(v, off, 64);
    if ((threadIdx.x & 63) == 0) red[threadIdx.x >> 6] = v;
    __syncthreads();
    if (threadIdx.x == 0) atomicAdd(S, (double)(red[0] + red[1] + red[2] + red[3]));
}

__global__ void loss_kernel(const float* __restrict__ dists, const double* __restrict__ Sd,
                            double* __restrict__ acc2) {
    int idx = blockIdx.x * 256 + threadIdx.x;
    float S = (float)Sd[0];
    float dv = dists[idx];
    float p = expf(-(dv / CONCENTRATION));
    float q = p / S;
    float e = q * logf(q + EPS);
    float p2 = expf(-(dv / TEMPERATURE));
    float nl = logf(p2 + EPS);
    __shared__ float rede[4];
    __shared__ float redn[4];
    for (int off = 32; off > 0; off >>= 1) { e += __shfl_down(e, off, 64); nl += __shfl_down(nl, off, 64); }
    if ((threadIdx.x & 63) == 0) { rede[threadIdx.x >> 6] = e; redn[threadIdx.x >> 6] = nl; }
    __syncthreads();
    if (threadIdx.x == 0) {
        atomicAdd(&acc2[0], (double)(rede[0] + rede[1] + rede[2] + rede[3]));
        atomicAdd(&acc2[1], (double)(redn[0] + redn[1] + redn[2] + redn[3]));
    }
}

__global__ void finalize_kernel(const double* __restrict__ acc2, float* __restrict__ out) {
    double kd = (double)(K * D);
    double entropy = acc2[0] / kd;
    double nll = -(acc2[1] / kd);
    out[0] = (float)(entropy + nll);
}

extern "C" void kernel_launch(void* const* d_in, const int* in_sizes, int n_in,
                              void* d_out, int out_size, void* d_ws, size_t ws_size,
                              hipStream_t stream) {
    const float* feats = (const float*)d_in[0];
    float* out = (float*)d_out;

    float* centroids = (float*)d_ws;              // K*D
    float* sums      = centroids + (size_t)K * D; // K*D
    float* dists     = sums + (size_t)K * D;      // K*D
    float* x_sq      = dists + (size_t)K * D;     // N
    float* c_sq      = x_sq + N;                  // K
    float* counts    = c_sq + K;                  // K
    int*   clusters  = (int*)(counts + K);        // N
    double* scal     = (double*)(clusters + N);   // [0]=S [1]=esum [2]=nsum

    hipMemcpyAsync(centroids, feats, (size_t)K * D * sizeof(float),
                   hipMemcpyDeviceToDevice, stream);
    rowsq_kernel<<<N / 4, 256, 0, stream>>>(feats, x_sq, N);

    for (int it = 0; it < NUM_ITERS; ++it) {
        rowsq_kernel<<<K / 4, 256, 0, stream>>>(centroids, c_sq, K);
        assign_kernel<<<N / TM, 256, 0, stream>>>(feats, centroids, x_sq, c_sq, clusters);
        hipMemsetAsync(sums, 0, (size_t)K * D * sizeof(float), stream);
        hipMemsetAsync(counts, 0, K * sizeof(float), stream);
        accum_kernel<<<N, 256, 0, stream>>>(feats, clusters, sums, counts);
        update_kernel<<<(K * D) / 256, 256, 0, stream>>>(centroids, sums, counts);
    }
    // final assignment with converged centroids
    rowsq_kernel<<<K / 4, 256, 0, stream>>>(centroids, c_sq, K);
    assign_kernel<<<N / TM, 256, 0, stream>>>(feats, centroids, x_sq, c_sq, clusters);

    hipMemsetAsync(dists, 0, (size_t)K * D * sizeof(float), stream);
    dist_kernel<<<N, 256, 0, stream>>>(feats, centroids, clusters, dists);

    hipMemsetAsync(scal, 0, 3 * sizeof(double), stream);
    sump_kernel<<<(K * D) / 256, 256, 0, stream>>>(dists, &scal[0]);
    loss_kernel<<<(K * D) / 256, 256, 0, stream>>>(dists, &scal[0], &scal[1]);
    finalize_kernel<<<1, 1, 0, stream>>>(&scal[1], out);
}

// Round 2
// 1513.584 us; speedup vs baseline: 2.6433x; 2.6433x over previous
//
#include <hip/hip_runtime.h>
#include <math.h>

#define N 16384
#define D 512
#define K 1024
#define NUM_ITERS 10
#define TEMPERATURE 0.1f
#define CONCENTRATION 0.1f
#define EPS 1e-6f

typedef unsigned short ushort_t;
typedef unsigned long long u64;
typedef __attribute__((ext_vector_type(4))) float floatx4;
typedef __attribute__((ext_vector_type(8))) short shortx8;

#define BM 128
#define BN 128
#define BK 32

// ---------- bf16 split helpers ----------
__device__ inline ushort_t f2bf(float f) {
    unsigned b = __float_as_uint(f);
    b += 0x7FFFu + ((b >> 16) & 1u);   // RNE
    return (ushort_t)(b >> 16);
}
__device__ inline float bf2f(ushort_t h) { return __uint_as_float(((unsigned)h) << 16); }

__device__ inline unsigned ford(float f) {   // order-preserving float->uint
    unsigned b = __float_as_uint(f);
    return (b & 0x80000000u) ? ~b : (b | 0x80000000u);
}

__device__ inline void gld16(const void* g, void* l) {
    __builtin_amdgcn_global_load_lds(
        (const __attribute__((address_space(1))) void*)(uintptr_t)(g),
        (__attribute__((address_space(3))) void*)(uintptr_t)(l), 16, 0, 0);
}

// ---------- split fp32 -> (hi, lo) bf16 ----------
__global__ void split_kernel(const float* __restrict__ x, ushort_t* __restrict__ hi,
                             ushort_t* __restrict__ lo, int n4) {
    int i = blockIdx.x * 256 + threadIdx.x;
    if (i >= n4) return;
    float4 v = ((const float4*)x)[i];
    ushort_t h0 = f2bf(v.x), h1 = f2bf(v.y), h2 = f2bf(v.z), h3 = f2bf(v.w);
    ushort4 hv = {h0, h1, h2, h3};
    ushort4 lv = {f2bf(v.x - bf2f(h0)), f2bf(v.y - bf2f(h1)),
                  f2bf(v.z - bf2f(h2)), f2bf(v.w - bf2f(h3))};
    ((ushort4*)hi)[i] = hv;
    ((ushort4*)lo)[i] = lv;
}

// ---------- row sum-of-squares (c_sq) ----------
__global__ void rowsq_kernel(const float* __restrict__ x, float* __restrict__ out, int rows) {
    int row = blockIdx.x * 4 + (threadIdx.x >> 6);
    int lane = threadIdx.x & 63;
    if (row >= rows) return;
    const float* r = x + (size_t)row * D;
    float s = 0.f;
    for (int i = lane; i < D; i += 64) { float v = r[i]; s += v * v; }
    for (int off = 32; off > 0; off >>= 1) s += __shfl_down(s, off, 64);
    if (lane == 0) out[row] = s;
}

// ---------- MFMA assign: per-point argmin_k (csq[k] - 2*dot(p,k)) ----------
__global__ __launch_bounds__(256) void assign_mfma(
    const ushort_t* __restrict__ Ah, const ushort_t* __restrict__ Al,
    const ushort_t* __restrict__ Bh, const ushort_t* __restrict__ Bl,
    const float* __restrict__ csq, u64* __restrict__ best)
{
    __shared__ __align__(16) ushort_t sAh[BM * BK];
    __shared__ __align__(16) ushort_t sAl[BM * BK];
    __shared__ __align__(16) ushort_t sBh[BN * BK];
    __shared__ __align__(16) ushort_t sBl[BN * BK];

    const int tid = threadIdx.x;
    const int lane = tid & 63;
    const int wave = tid >> 6;
    const int wr = wave >> 1, wc = wave & 1;     // 2x2 wave grid, each wave 64x64
    const int quad = lane >> 4, l16 = lane & 15;

    const int brow = (int)blockIdx.x >> 3;       // 128 row-tiles
    const int bcol = (int)blockIdx.x & 7;        // 8 col-tiles
    const int row0 = brow * BM, col0 = bcol * BN;

    floatx4 acc[4][4];
#pragma unroll
    for (int a = 0; a < 4; ++a)
#pragma unroll
        for (int b = 0; b < 4; ++b) acc[a][b] = (floatx4){0.f, 0.f, 0.f, 0.f};

    // staging: chunk c = iter*256+tid; logical (row = c>>2, d = (c&3)*8), lds offset c*16B
    const int r_a = tid >> 2;
    const int dp = (tid & 3) * 8;

    for (int d0 = 0; d0 < D; d0 += BK) {
        __syncthreads();
        {
            const size_t ga0 = (size_t)(row0 + r_a) * D + d0 + dp;
            const size_t ga1 = (size_t)(row0 + r_a + 64) * D + d0 + dp;
            const size_t gb0 = (size_t)(col0 + r_a) * D + d0 + dp;
            const size_t gb1 = (size_t)(col0 + r_a + 64) * D + d0 + dp;
            const int l0 = tid * 8;
            const int l1 = (tid + 256) * 8;
            gld16(Ah + ga0, sAh + l0); gld16(Ah + ga1, sAh + l1);
            gld16(Al + ga0, sAl + l0); gld16(Al + ga1, sAl + l1);
            gld16(Bh + gb0, sBh + l0); gld16(Bh + gb1, sBh + l1);
            gld16(Bl + gb0, sBl + l0); gld16(Bl + gb1, sBl + l1);
        }
        __syncthreads();

        shortx8 fah[4], fal[4], fbh[4], fbl[4];
#pragma unroll
        for (int t = 0; t < 4; ++t) {
            const int ar = wr * 64 + t * 16 + l16;
            const int bc = wc * 64 + t * 16 + l16;
            fah[t] = *(const shortx8*)&sAh[ar * BK + quad * 8];
            fal[t] = *(const shortx8*)&sAl[ar * BK + quad * 8];
            fbh[t] = *(const shortx8*)&sBh[bc * BK + quad * 8];
            fbl[t] = *(const shortx8*)&sBl[bc * BK + quad * 8];
        }
#pragma unroll
        for (int i = 0; i < 4; ++i)
#pragma unroll
            for (int j = 0; j < 4; ++j) {
                acc[i][j] = __builtin_amdgcn_mfma_f32_16x16x32_bf16(fah[i], fbh[j], acc[i][j], 0, 0, 0);
                acc[i][j] = __builtin_amdgcn_mfma_f32_16x16x32_bf16(fah[i], fbl[j], acc[i][j], 0, 0, 0);
                acc[i][j] = __builtin_amdgcn_mfma_f32_16x16x32_bf16(fal[i], fbh[j], acc[i][j], 0, 0, 0);
            }
    }

    // epilogue: dist proxy = csq[k] - 2*dot ; argmin with first-min tie break
    float csqv[4];
#pragma unroll
    for (int j = 0; j < 4; ++j) csqv[j] = csq[col0 + wc * 64 + j * 16 + l16];

    const int k0 = col0 + wc * 64 + l16;
#pragma unroll
    for (int i = 0; i < 4; ++i) {
#pragma unroll
        for (int r = 0; r < 4; ++r) {
            float bv = csqv[0] - 2.0f * acc[i][0][r];
            int bk = k0;
#pragma unroll
            for (int j = 1; j < 4; ++j) {
                float v = csqv[j] - 2.0f * acc[i][j][r];
                int kk = k0 + j * 16;
                if (v < bv || (v == bv && kk < bk)) { bv = v; bk = kk; }
            }
#pragma unroll
            for (int m = 1; m < 16; m <<= 1) {
                float ov = __shfl_xor(bv, m, 64);
                int ok = __shfl_xor(bk, m, 64);
                if (ov < bv || (ov == bv && ok < bk)) { bv = ov; bk = ok; }
            }
            if (l16 == 0) {
                int p = row0 + wr * 64 + i * 16 + quad * 4 + r;
                u64 pk = ((u64)ford(bv) << 32) | (unsigned)bk;
                atomicMin(&best[p], pk);
            }
        }
    }
}

__global__ void convert_kernel(const u64* __restrict__ best, int* __restrict__ clusters) {
    int p = blockIdx.x * 256 + threadIdx.x;
    clusters[p] = (int)(unsigned)(best[p] & 0xFFFFFFFFull);
}

// ---------- segment sums (atomic) ----------
__global__ void accum_kernel(const float* __restrict__ feats, const int* __restrict__ clusters,
                             float* __restrict__ sums, float* __restrict__ counts) {
    int p = blockIdx.x;
    int cl = clusters[p];
    const float* row = feats + (size_t)p * D;
    float* srow = sums + (size_t)cl * D;
    for (int d = threadIdx.x; d < D; d += 256) atomicAdd(&srow[d], row[d]);
    if (threadIdx.x == 0) atomicAdd(&counts[cl], 1.0f);
}

__global__ void update_kernel(float* __restrict__ cent, const float* __restrict__ sums,
                              const float* __restrict__ counts) {
    int idx = blockIdx.x * 256 + threadIdx.x;
    int k = idx >> 9;
    float cnt = counts[k];
    if (cnt > 0.f) cent[idx] = sums[idx] / fmaxf(cnt, 1.f);
}

// ---------- residual^2 segment sum ----------
__global__ void dist_kernel(const float* __restrict__ feats, const float* __restrict__ cent,
                            const int* __restrict__ clusters, float* __restrict__ dists) {
    int p = blockIdx.x;
    int cl = clusters[p];
    const float* row = feats + (size_t)p * D;
    const float* crow = cent + (size_t)cl * D;
    float* drow = dists + (size_t)cl * D;
    for (int d = threadIdx.x; d < D; d += 256) {
        float r = row[d] - crow[d];
        atomicAdd(&drow[d], r * r);
    }
}

// ---------- loss ----------
__global__ void sump_kernel(const float* __restrict__ dists, double* __restrict__ S) {
    int idx = blockIdx.x * 256 + threadIdx.x;
    float v = expf(-(dists[idx] / CONCENTRATION));
    __shared__ float red[4];
    for (int off = 32; off > 0; off >>= 1) v += __shfl_down(v, off, 64);
    if ((threadIdx.x & 63) == 0) red[threadIdx.x >> 6] = v;
    __syncthreads();
    if (threadIdx.x == 0) atomicAdd(S, (double)(red[0] + red[1] + red[2] + red[3]));
}

__global__ void loss_kernel(const float* __restrict__ dists, const double* __restrict__ Sd,
                            double* __restrict__ acc2) {
    int idx = blockIdx.x * 256 + threadIdx.x;
    float S = (float)Sd[0];
    float dv = dists[idx];
    float p = expf(-(dv / CONCENTRATION));
    float q = p / S;
    float e = q * logf(q + EPS);
    float p2 = expf(-(dv / TEMPERATURE));
    float nl = logf(p2 + EPS);
    __shared__ float rede[4];
    __shared__ float redn[4];
    for (int off = 32; off > 0; off >>= 1) { e += __shfl_down(e, off, 64); nl += __shfl_down(nl, off, 64); }
    if ((threadIdx.x & 63) == 0) { rede[threadIdx.x >> 6] = e; redn[threadIdx.x >> 6] = nl; }
    __syncthreads();
    if (threadIdx.x == 0) {
        atomicAdd(&acc2[0], (double)(rede[0] + rede[1] + rede[2] + rede[3]));
        atomicAdd(&acc2[1], (double)(redn[0] + redn[1] + redn[2] + redn[3]));
    }
}

__global__ void finalize_kernel(const double* __restrict__ acc2, float* __restrict__ out) {
    double kd = (double)(K * D);
    double entropy = acc2[0] / kd;
    double nll = -(acc2[1] / kd);
    out[0] = (float)(entropy + nll);
}

extern "C" void kernel_launch(void* const* d_in, const int* in_sizes, int n_in,
                              void* d_out, int out_size, void* d_ws, size_t ws_size,
                              hipStream_t stream) {
    const float* feats = (const float*)d_in[0];
    float* out = (float*)d_out;

    ushort_t* Ah = (ushort_t*)d_ws;               // N*D
    ushort_t* Al = Ah + (size_t)N * D;            // N*D
    ushort_t* Bh = Al + (size_t)N * D;            // K*D
    ushort_t* Bl = Bh + (size_t)K * D;            // K*D
    float* centroids = (float*)(Bl + (size_t)K * D); // K*D
    float* sums      = centroids + (size_t)K * D;    // K*D
    float* dists     = sums + (size_t)K * D;         // K*D
    float* csq       = dists + (size_t)K * D;        // K
    float* counts    = csq + K;                      // K
    int*   clusters  = (int*)(counts + K);           // N
    u64*   best      = (u64*)(clusters + N);         // N
    double* scal     = (double*)(best + N);          // 3

    split_kernel<<<(N * D / 4) / 256, 256, 0, stream>>>(feats, Ah, Al, N * D / 4);
    hipMemcpyAsync(centroids, feats, (size_t)K * D * sizeof(float),
                   hipMemcpyDeviceToDevice, stream);

    for (int it = 0; it < NUM_ITERS; ++it) {
        split_kernel<<<(K * D / 4) / 256, 256, 0, stream>>>(centroids, Bh, Bl, K * D / 4);
        rowsq_kernel<<<K / 4, 256, 0, stream>>>(centroids, csq, K);
        hipMemsetAsync(best, 0xFF, (size_t)N * sizeof(u64), stream);
        assign_mfma<<<(N / BM) * (K / BN), 256, 0, stream>>>(Ah, Al, Bh, Bl, csq, best);
        convert_kernel<<<N / 256, 256, 0, stream>>>(best, clusters);
        hipMemsetAsync(sums, 0, (size_t)K * D * sizeof(float), stream);
        hipMemsetAsync(counts, 0, K * sizeof(float), stream);
        accum_kernel<<<N, 256, 0, stream>>>(feats, clusters, sums, counts);
        update_kernel<<<(K * D) / 256, 256, 0, stream>>>(centroids, sums, counts);
    }
    // final assignment with converged centroids
    split_kernel<<<(K * D / 4) / 256, 256, 0, stream>>>(centroids, Bh, Bl, K * D / 4);
    rowsq_kernel<<<K / 4, 256, 0, stream>>>(centroids, csq, K);
    hipMemsetAsync(best, 0xFF, (size_t)N * sizeof(u64), stream);
    assign_mfma<<<(N / BM) * (K / BN), 256, 0, stream>>>(Ah, Al, Bh, Bl, csq, best);
    convert_kernel<<<N / 256, 256, 0, stream>>>(best, clusters);

    hipMemsetAsync(dists, 0, (size_t)K * D * sizeof(float), stream);
    dist_kernel<<<N, 256, 0, stream>>>(feats, centroids, clusters, dists);

    hipMemsetAsync(scal, 0, 3 * sizeof(double), stream);
    sump_kernel<<<(K * D) / 256, 256, 0, stream>>>(dists, &scal[0]);
    loss_kernel<<<(K * D) / 256, 256, 0, stream>>>(dists, &scal[0], &scal[1]);
    finalize_kernel<<<1, 1, 0, stream>>>(&scal[1], out);
}